// Round 4
// baseline (195.744 us; speedup 1.0000x reference)
//
#include <hip/hip_runtime.h>

#define B_     16
#define D_     256
#define HEADS_ 8
#define N_     32
#define H_     56
#define W_     56
#define L_     3136
#define LDB    40   // bf16 LDS row stride for proj B-tile (80 B, 16B-aligned rows)
#define LDX    66   // fp32 LDS row stride for x tile (264 B, 8B-aligned, banks spread)

typedef short short8 __attribute__((ext_vector_type(8)));
typedef float f32x4  __attribute__((ext_vector_type(4)));

__device__ __forceinline__ unsigned short f2bf(float f) {
    union { float f; unsigned u; } c; c.f = f;
    unsigned u = c.u;
    u += 0x7fffu + ((u >> 16) & 1u);   // RNE
    return (unsigned short)(u >> 16);
}

// ---------------------------------------------------------------------------
// Wk, Wv, Wproj fp32 -> bf16
// ---------------------------------------------------------------------------
__global__ __launch_bounds__(256) void convert_w_kernel(
    const float* __restrict__ w0, const float* __restrict__ w1,
    const float* __restrict__ w2, unsigned short* __restrict__ o0,
    unsigned short* __restrict__ o1, unsigned short* __restrict__ o2)
{
    const float* src; unsigned short* dst;
    if (blockIdx.y == 0)      { src = w0; dst = o0; }
    else if (blockIdx.y == 1) { src = w1; dst = o1; }
    else                      { src = w2; dst = o2; }
    const int i = (blockIdx.x * 256 + threadIdx.x) * 4;
    float4 v = *(const float4*)(src + i);
    uint2 o;
    o.x = (unsigned)f2bf(v.x) | ((unsigned)f2bf(v.y) << 16);
    o.y = (unsigned)f2bf(v.z) | ((unsigned)f2bf(v.w) << 16);
    *(uint2*)(dst + i) = o;
}

// ---------------------------------------------------------------------------
// K/V projection. BM=256 (all d), BN=64 (l), BK=32 (c), 4 waves.
// x read fp32 directly (no pre-transpose); B-frags assembled from natural-
// layout fp32 LDS tile via strided ds_read_b32 + on-the-fly bf16 convert.
// Weights read as A-frags straight from global (L2-hot, 128 KB each).
// Outputs: V bf16 in [b*h][l][32] layout, S = q.K fp32 (K never stored).
// ---------------------------------------------------------------------------
__global__ __launch_bounds__(256, 2) void gemm_kv_mfma(
    const float* __restrict__ x, const unsigned short* __restrict__ Wkb,
    const unsigned short* __restrict__ Wvb, const float* __restrict__ q,
    unsigned short* __restrict__ Vo, float* __restrict__ S)
{
    __shared__ float Xs[32][LDX];

    const int bb = blockIdx.z;
    const int l0 = blockIdx.x * 64;
    const int t  = threadIdx.x;
    const int w    = t >> 6;
    const int lane = t & 63;
    const int col  = lane & 15;
    const int quad = lane >> 4;

    f32x4 accK[4][4], accV[4][4];
#pragma unroll
    for (int mi = 0; mi < 4; ++mi)
#pragma unroll
        for (int ni = 0; ni < 4; ++ni) {
            accK[mi][ni] = (f32x4){0.f, 0.f, 0.f, 0.f};
            accV[mi][ni] = (f32x4){0.f, 0.f, 0.f, 0.f};
        }

    const int xc = t >> 3;          // c-row 0..31
    const int xl = (t & 7) * 8;     // l offset
    const float* xrow = x + ((size_t)bb * D_ + xc) * L_ + l0 + xl;

    const unsigned short* wk0 = Wkb + (size_t)(w * 64 + col) * D_ + quad * 8;
    const unsigned short* wv0 = Wvb + (size_t)(w * 64 + col) * D_ + quad * 8;

    for (int kt = 0; kt < 8; ++kt) {
        const int c0 = kt * 32;
        const float* xp = xrow + (size_t)c0 * L_;
        float4 x0 = *(const float4*)xp;
        float4 x1 = *(const float4*)(xp + 4);
        short8 ak[4], av[4];
#pragma unroll
        for (int mi = 0; mi < 4; ++mi) {
            ak[mi] = *(const short8*)(wk0 + (size_t)mi * 16 * D_ + c0);
            av[mi] = *(const short8*)(wv0 + (size_t)mi * 16 * D_ + c0);
        }

        __syncthreads();
        *(float2*)&Xs[xc][xl + 0] = make_float2(x0.x, x0.y);
        *(float2*)&Xs[xc][xl + 2] = make_float2(x0.z, x0.w);
        *(float2*)&Xs[xc][xl + 4] = make_float2(x1.x, x1.y);
        *(float2*)&Xs[xc][xl + 6] = make_float2(x1.z, x1.w);
        __syncthreads();

        short8 bfr[4];
#pragma unroll
        for (int ni = 0; ni < 4; ++ni)
#pragma unroll
            for (int j = 0; j < 8; ++j)
                bfr[ni][j] = (short)f2bf(Xs[quad * 8 + j][ni * 16 + col]);

#pragma unroll
        for (int mi = 0; mi < 4; ++mi)
#pragma unroll
            for (int ni = 0; ni < 4; ++ni) {
                accK[mi][ni] = __builtin_amdgcn_mfma_f32_16x16x32_bf16(ak[mi], bfr[ni], accK[mi][ni], 0, 0, 0);
                accV[mi][ni] = __builtin_amdgcn_mfma_f32_16x16x32_bf16(av[mi], bfr[ni], accV[mi][ni], 0, 0, 0);
            }
    }

    // ---- V epilogue: Vo[(bh*L + l)*32 + (d&31)], 4 packed bf16 per store ----
#pragma unroll
    for (int mi = 0; mi < 4; ++mi) {
        const int hh = w * 2 + (mi >> 1);
        const int dn = (mi & 1) * 16 + quad * 4;
#pragma unroll
        for (int ni = 0; ni < 4; ++ni) {
            unsigned short pk[4];
#pragma unroll
            for (int r = 0; r < 4; ++r) pk[r] = f2bf(accV[mi][ni][r]);
            const int l = l0 + ni * 16 + col;
            *(uint2*)(Vo + ((((size_t)(bb * HEADS_ + hh)) * L_ + l) << 5) + dn) =
                *(const uint2*)pk;
        }
    }

    // ---- S epilogue: S[b,h,l] = q . K (wave covers heads 2w, 2w+1) ----
    float qv[4][4];
#pragma unroll
    for (int mi = 0; mi < 4; ++mi)
#pragma unroll
        for (int r = 0; r < 4; ++r)
            qv[mi][r] = q[bb * D_ + w * 64 + mi * 16 + quad * 4 + r];

#pragma unroll
    for (int ni = 0; ni < 4; ++ni) {
        float s0 = 0.f, s1 = 0.f;
#pragma unroll
        for (int r = 0; r < 4; ++r) {
            s0 = fmaf(qv[0][r], accK[0][ni][r], s0);
            s0 = fmaf(qv[1][r], accK[1][ni][r], s0);
            s1 = fmaf(qv[2][r], accK[2][ni][r], s1);
            s1 = fmaf(qv[3][r], accK[3][ni][r], s1);
        }
        s0 += __shfl_xor(s0, 16, 64);
        s0 += __shfl_xor(s0, 32, 64);
        s1 += __shfl_xor(s1, 16, 64);
        s1 += __shfl_xor(s1, 32, 64);
        if (lane < 16) {
            const int l = l0 + ni * 16 + col;
            S[(size_t)(bb * HEADS_ + w * 2) * L_ + l]     = s0;
            S[(size_t)(bb * HEADS_ + w * 2 + 1) * L_ + l] = s1;
        }
    }
}

// ---------------------------------------------------------------------------
// attend: LDS-staged. Block = (8-row band, 8-ch group, b*h).
// V is [bh][l][32] so staging is one uint4 per position (halo -> zeros,
// reproducing padded-K/V semantics).
// ---------------------------------------------------------------------------
__global__ __launch_bounds__(256) void attend_kernel(
    const float* __restrict__ S, const unsigned short* __restrict__ Vo,
    const float* __restrict__ pos_emb, const float* __restrict__ Wlin,
    unsigned short* __restrict__ Om)
{
    __shared__ unsigned short Vs[10][58][8];   // 9.28 KB
    __shared__ float Ss[10][58];               // 2.3 KB

    const int band = blockIdx.x;   // 0..6
    const int half = blockIdx.y;   // 0..3
    const int bh   = blockIdx.z;   // 0..127
    const int y0   = band * 8;
    const int t    = threadIdx.x;

    const float* Sb = S + (size_t)bh * L_;
    for (int j = t; j < 580; j += 256) {
        const int row = j / 58, c = j - row * 58;
        const int gr = y0 - 1 + row, gc = c - 1;
        const bool in = (gr >= 0 && gr < H_ && gc >= 0 && gc < W_);
        Ss[row][c] = in ? Sb[gr * W_ + gc] : 0.f;
        uint4 vv = make_uint4(0u, 0u, 0u, 0u);
        if (in)
            vv = *(const uint4*)(Vo + (((size_t)bh * L_ + gr * W_ + gc) << 5) + half * 8);
        *(uint4*)&Vs[row][c][0] = vv;
    }
    __syncthreads();

    const float scale = Wlin[0] + Wlin[1] + Wlin[2] + Wlin[3];
    const float pe0 = pos_emb[0], pe1 = pos_emb[1], pe2 = pos_emb[2];
    const float pe3 = pos_emb[3], pe4 = pos_emb[4];
    const float bias[9] = {pe0, pe1, pe2, pe1, pe2, pe3, pe2, pe3, pe4};

    for (int p = t; p < 448; p += 256) {
        const int yl = p / 56, xx = p - yl * 56;
        const int lr = yl + 1, lc = xx + 1;

        float lg[9], m = -1e30f;
#pragma unroll
        for (int dy = 0; dy < 3; ++dy)
#pragma unroll
            for (int dx = 0; dx < 3; ++dx) {
                const int k = dy * 3 + dx;
                lg[k] = Ss[lr - 1 + dy][lc - 1 + dx] + bias[k];
                m = fmaxf(m, lg[k]);
            }
        float ssum = 0.f;
#pragma unroll
        for (int k = 0; k < 9; ++k) { lg[k] = __expf(lg[k] - m); ssum += lg[k]; }
        const float inv = scale / ssum;

        float om[8] = {0.f, 0.f, 0.f, 0.f, 0.f, 0.f, 0.f, 0.f};
#pragma unroll
        for (int dy = 0; dy < 3; ++dy)
#pragma unroll
            for (int dx = 0; dx < 3; ++dx) {
                const float wk = lg[dy * 3 + dx] * inv;
                const uint4 v = *(const uint4*)&Vs[lr - 1 + dy][lc - 1 + dx][0];
                const unsigned* u = (const unsigned*)&v;
#pragma unroll
                for (int i = 0; i < 4; ++i) {
                    union { unsigned uu; float f; } lo, hi;
                    lo.uu = u[i] << 16;
                    hi.uu = u[i] & 0xffff0000u;
                    om[2 * i]     = fmaf(wk, lo.f, om[2 * i]);
                    om[2 * i + 1] = fmaf(wk, hi.f, om[2 * i + 1]);
                }
            }

        unsigned short ob[8];
#pragma unroll
        for (int i = 0; i < 8; ++i) ob[i] = f2bf(om[i]);
        const int l = (y0 + yl) * W_ + xx;
        *(uint4*)(Om + (((size_t)bh * L_ + l) << 5) + half * 8) = *(const uint4*)ob;
    }
}

// ---------------------------------------------------------------------------
// out = Wproj @ Om. BM=256 (all d, Om read ONCE), BN=64. A-frags from global.
// Om [b][h][l][32]: head == K-chunk, rows are contiguous 32-bf16 runs.
// ---------------------------------------------------------------------------
__global__ __launch_bounds__(256, 2) void gemm_proj_mfma(
    const unsigned short* __restrict__ Om, const unsigned short* __restrict__ Wpb,
    float* __restrict__ Out)
{
    __shared__ unsigned short Bs[64][LDB];

    const int bb = blockIdx.z;
    const int l0 = blockIdx.x * 64;
    const int t  = threadIdx.x;
    const int w    = t >> 6;
    const int lane = t & 63;
    const int col  = lane & 15;
    const int quad = lane >> 4;

    f32x4 acc[4][4];
#pragma unroll
    for (int mi = 0; mi < 4; ++mi)
#pragma unroll
        for (int ni = 0; ni < 4; ++ni) acc[mi][ni] = (f32x4){0.f, 0.f, 0.f, 0.f};

    const int srow = t >> 2;        // 0..63
    const int skc  = (t & 3) * 8;
    const unsigned short* wp0 = Wpb + (size_t)(w * 64 + col) * D_ + quad * 8;

    for (int kt = 0; kt < 8; ++kt) {
        const int c0 = kt * 32;
        uint4 bg = *(const uint4*)(Om +
            ((((size_t)(bb * HEADS_ + kt)) * L_ + l0 + srow) << 5) + skc);
        short8 a[4];
#pragma unroll
        for (int mi = 0; mi < 4; ++mi)
            a[mi] = *(const short8*)(wp0 + (size_t)mi * 16 * D_ + c0);

        __syncthreads();
        *(uint4*)&Bs[srow][skc] = bg;
        __syncthreads();

        short8 bfr[4];
#pragma unroll
        for (int ni = 0; ni < 4; ++ni)
            bfr[ni] = *(const short8*)&Bs[ni * 16 + col][quad * 8];

#pragma unroll
        for (int mi = 0; mi < 4; ++mi)
#pragma unroll
            for (int ni = 0; ni < 4; ++ni)
                acc[mi][ni] = __builtin_amdgcn_mfma_f32_16x16x32_bf16(a[mi], bfr[ni], acc[mi][ni], 0, 0, 0);
    }

#pragma unroll
    for (int mi = 0; mi < 4; ++mi)
#pragma unroll
        for (int ni = 0; ni < 4; ++ni)
#pragma unroll
            for (int r = 0; r < 4; ++r) {
                const int d = w * 64 + mi * 16 + quad * 4 + r;
                const int l = l0 + ni * 16 + col;
                Out[((size_t)bb * D_ + d) * L_ + l] = acc[mi][ni][r];
            }
}

// ---------------------------------------------------------------------------
extern "C" void kernel_launch(void* const* d_in, const int* in_sizes, int n_in,
                              void* d_out, int out_size, void* d_ws, size_t ws_size,
                              hipStream_t stream)
{
    const float* x       = (const float*)d_in[0];
    const float* q       = (const float*)d_in[1];
    const float* Wk      = (const float*)d_in[2];
    const float* Wv      = (const float*)d_in[3];
    const float* pos_emb = (const float*)d_in[4];
    const float* Wlin    = (const float*)d_in[5];
    const float* Wproj   = (const float*)d_in[6];
    float* out = (float*)d_out;

    const size_t planeE = (size_t)B_ * D_ * L_;      // 12,845,056 elems
    unsigned short* Vo  = (unsigned short*)d_ws;
    unsigned short* Om  = Vo + planeE;
    unsigned short* Wkb = Om + planeE;
    unsigned short* Wvb = Wkb + D_ * D_;
    unsigned short* Wpb = Wvb + D_ * D_;
    float*          S   = (float*)(Wpb + D_ * D_);   // B*8*L fp32

    convert_w_kernel<<<dim3(64, 3), 256, 0, stream>>>(Wk, Wv, Wproj, Wkb, Wvb, Wpb);
    gemm_kv_mfma<<<dim3(L_ / 64, 1, B_), 256, 0, stream>>>(x, Wkb, Wvb, q, Vo, S);
    attend_kernel<<<dim3(7, 4, B_ * HEADS_), 256, 0, stream>>>(
        S, Vo, pos_emb, Wlin, Om);
    gemm_proj_mfma<<<dim3(L_ / 64, 1, B_), 256, 0, stream>>>(Om, Wpb, out);
}